// Round 4
// baseline (317.154 us; speedup 1.0000x reference)
//
#include <hip/hip_runtime.h>
#include <hip/hip_bf16.h>
#include <math.h>

typedef _Float16 f16x4 __attribute__((ext_vector_type(4)));
typedef _Float16 f16x8 __attribute__((ext_vector_type(8)));
typedef float f32x4 __attribute__((ext_vector_type(4)));
typedef __fp16 hf2 __attribute__((ext_vector_type(2)));
typedef __fp16 hf8 __attribute__((ext_vector_type(8)));

struct hf2x4 { hf2 a, b, c, d; };   // 16B view of hf8 as 4 half2s

#define DIM 128
#define LDST 136   // padded LDS row stride in f16 elems (272B, 16B-aligned)

// ---------------------------------------------------------------------------
// Kernel 1: transpose + f16-convert the three 128x128 weight matrices.
// ---------------------------------------------------------------------------
__global__ __launch_bounds__(256) void prep_w_kernel(
    const float* __restrict__ Wq, const float* __restrict__ Wk,
    const float* __restrict__ Wv, _Float16* __restrict__ Wt)
{
    const float* W = (blockIdx.y == 0) ? Wq : (blockIdx.y == 1) ? Wk : Wv;
    _Float16* dst = Wt + (size_t)blockIdx.y * DIM * DIM;
    int idx = blockIdx.x * 256 + threadIdx.x;
    int k = idx >> 7;
    int n = idx & 127;
    dst[n * DIM + k] = (_Float16)W[idx];
}

// ---------------------------------------------------------------------------
// Kernel 2: fused projection GEMM  Y = gelu(X @ W + b), output f16.
// (identical to R3 — coalesced LDS-staged A, MFMA, LDS-transposed epilogue)
// ---------------------------------------------------------------------------
__global__ __launch_bounds__(256, 2) void proj_gemm_kernel(
    const float* __restrict__ query, const float* __restrict__ memory,
    const _Float16* __restrict__ Wt,
    const float* __restrict__ bq, const float* __restrict__ bk,
    const float* __restrict__ bv,
    _Float16* __restrict__ qf, _Float16* __restrict__ kv, int n, int m)
{
    __shared__ _Float16 xs[128 * LDST];   // 34816 B

    int which = blockIdx.y;
    const float* X    = (which == 0) ? query : memory;
    const _Float16* Wm = Wt + (size_t)which * DIM * DIM;
    const float* bias = (which == 0) ? bq : (which == 1) ? bk : bv;
    int R             = (which == 0) ? n : m;
    _Float16* Ybase   = (which == 0) ? qf : (which == 2) ? kv + DIM : kv;
    size_t Ystride    = (which == 0) ? DIM : 2 * DIM;

    int tid = threadIdx.x;
    int rowblock = blockIdx.x * 128;
    if (rowblock >= R) return;

    for (int it = 0; it < 16; ++it) {
        int flat = it * 256 + tid;
        int r  = flat >> 5;
        int c4 = (flat & 31) * 4;
        int gr = rowblock + r;
        if (gr >= R) gr = R - 1;
        float4 x = *(const float4*)(X + (size_t)gr * DIM + c4);
        f16x4 w4;
        w4[0] = (_Float16)x.x; w4[1] = (_Float16)x.y;
        w4[2] = (_Float16)x.z; w4[3] = (_Float16)x.w;
        *(f16x4*)(&xs[r * LDST + c4]) = w4;
    }
    __syncthreads();

    int wave = tid >> 6;
    int lane = tid & 63;
    int quad = lane >> 4;
    int l16  = lane & 15;
    int wrow = wave * 32;

    f16x8 afrag[2][4];
    for (int rt = 0; rt < 2; ++rt)
        for (int ks = 0; ks < 4; ++ks)
            afrag[rt][ks] = *(const f16x8*)(&xs[(wrow + rt * 16 + l16) * LDST + quad * 8 + ks * 32]);

    f32x4 acc[8][2];
    for (int ct = 0; ct < 8; ++ct) { acc[ct][0] = {0,0,0,0}; acc[ct][1] = {0,0,0,0}; }
    for (int ct = 0; ct < 8; ++ct) {
        const _Float16* wp = Wm + (size_t)(ct * 16 + l16) * DIM + quad * 8;
        for (int ks = 0; ks < 4; ++ks) {
            f16x8 b = *(const f16x8*)(wp + ks * 32);
            acc[ct][0] = __builtin_amdgcn_mfma_f32_16x16x32_f16(afrag[0][ks], b, acc[ct][0], 0, 0, 0);
            acc[ct][1] = __builtin_amdgcn_mfma_f32_16x16x32_f16(afrag[1][ks], b, acc[ct][1], 0, 0, 0);
        }
    }

    __syncthreads();
    for (int ct = 0; ct < 8; ++ct) {
        float bval = bias[ct * 16 + l16];
        for (int rt = 0; rt < 2; ++rt) {
            for (int reg = 0; reg < 4; ++reg) {
                float x = acc[ct][rt][reg] + bval;
                float t  = 0.7978845608028654f * (x + 0.044715f * x * x * x);
                float th = 1.0f - 2.0f / (__expf(2.0f * t) + 1.0f);
                float g  = 0.5f * x * (1.0f + th);
                xs[(wrow + rt * 16 + quad * 4 + reg) * LDST + ct * 16 + l16] = (_Float16)g;
            }
        }
    }
    __syncthreads();

    for (int it = 0; it < 8; ++it) {
        int flat = it * 256 + tid;
        int r  = flat >> 4;
        int c8 = (flat & 15) * 8;
        int gr = rowblock + r;
        if (gr < R) {
            f16x8 vv = *(const f16x8*)(&xs[r * LDST + c8]);
            *(f16x8*)(Ybase + (size_t)gr * Ystride + c8) = vv;
        }
    }
}

// ---------------------------------------------------------------------------
// Kernel 3: per-row edge attention. One wave per row.
// 8 lanes/edge (l8 = lane&7 covers dims [l8*16, l8*16+16)), 16 edges in
// flight (slots g8 = lane>>3 for A, +8 for B). Plain exp (scores are O(1):
// |q.k|/sqrt(128) <= ~2, so no max-shift needed — matches reference softmax
// to fp32 rounding). Row range found by in-kernel binary search (lanes 0/1).
// kv interleaved: 512B record per col.
// ---------------------------------------------------------------------------
#if defined(__has_builtin)
#if __has_builtin(__builtin_amdgcn_fdot2)
#define HAVE_FDOT2 1
#endif
#endif

__device__ __forceinline__ void dot8(float& d, hf8 k8, hf8 q8) {
#ifdef HAVE_FDOT2
    hf2x4 K = __builtin_bit_cast(hf2x4, k8);
    hf2x4 Q = __builtin_bit_cast(hf2x4, q8);
    d = __builtin_amdgcn_fdot2(K.a, Q.a, d, false);
    d = __builtin_amdgcn_fdot2(K.b, Q.b, d, false);
    d = __builtin_amdgcn_fdot2(K.c, Q.c, d, false);
    d = __builtin_amdgcn_fdot2(K.d, Q.d, d, false);
#else
#pragma unroll
    for (int j = 0; j < 8; ++j) d += (float)k8[j] * (float)q8[j];
#endif
}

__global__ __launch_bounds__(256) void edge_attn_kernel(
    const __fp16* __restrict__ qf, const __fp16* __restrict__ kv,
    const float* __restrict__ adj_vals, const int* __restrict__ cols,
    const int* __restrict__ rows, float* __restrict__ out, int n, int e)
{
    int row = blockIdx.x * 4 + (threadIdx.x >> 6);
    if (row >= n) return;
    int lane = threadIdx.x & 63;
    int g8 = lane >> 3;   // edge slot 0..7
    int l8 = lane & 7;    // dim group: 16 dims

    // fused CSR range: lanes search lower_bound(row + (lane&1))
    int target = row + (lane & 1);
    int lo = 0, hi = e;
    while (lo < hi) {
        int mid = (lo + hi) >> 1;
        if (rows[mid] < target) lo = mid + 1; else hi = mid;
    }
    int start = __shfl(lo, 0);
    int end   = __shfl(lo, 1);

    const __fp16* qp = qf + (size_t)row * DIM + l8 * 16;
    hf8 q_lo = *(const hf8*)qp;
    hf8 q_hi = *(const hf8*)(qp + 8);

    float s_sum = 0.0f;
    float acc[16];
#pragma unroll
    for (int j = 0; j < 16; ++j) acc[j] = 0.0f;

    const float scale = 0.08838834764831845f;   // 1/sqrt(128)

    for (int base = start; base < end; base += 16) {
        int eA = base + g8;
        int eB = base + 8 + g8;
        bool vA = eA < end;
        bool vB = eB < end;
        int last = end - 1;
        int iA = vA ? eA : last;
        int iB = vB ? eB : last;
        int cA = cols[iA];
        int cB = cols[iB];
        float aA = adj_vals[iA] * scale;
        float aB = adj_vals[iB] * scale;

        const __fp16* pA = kv + (size_t)cA * 256 + l8 * 16;
        const __fp16* pB = kv + (size_t)cB * 256 + l8 * 16;
        hf8 kA0 = *(const hf8*)pA;
        hf8 kA1 = *(const hf8*)(pA + 8);
        hf8 vA0 = *(const hf8*)(pA + 128);
        hf8 vA1 = *(const hf8*)(pA + 136);
        hf8 kB0 = *(const hf8*)pB;
        hf8 kB1 = *(const hf8*)(pB + 8);
        hf8 vB0 = *(const hf8*)(pB + 128);
        hf8 vB1 = *(const hf8*)(pB + 136);

        float dA = 0.0f, dB = 0.0f;
        dot8(dA, kA0, q_lo); dot8(dA, kA1, q_hi);
        dot8(dB, kB0, q_lo); dot8(dB, kB1, q_hi);
        // reduce across the 8 lanes of this edge's group
        dA += __shfl_xor(dA, 1); dB += __shfl_xor(dB, 1);
        dA += __shfl_xor(dA, 2); dB += __shfl_xor(dB, 2);
        dA += __shfl_xor(dA, 4); dB += __shfl_xor(dB, 4);

        float pA_ = vA ? __expf(dA * aA) : 0.0f;
        float pB_ = vB ? __expf(dB * aB) : 0.0f;
        s_sum += pA_ + pB_;
#pragma unroll
        for (int j = 0; j < 8; ++j) acc[j]     += pA_ * (float)vA0[j] + pB_ * (float)vB0[j];
#pragma unroll
        for (int j = 0; j < 8; ++j) acc[j + 8] += pA_ * (float)vA1[j] + pB_ * (float)vB1[j];
    }

    // merge the 8 edge-slot groups (lanes differing in bits 3..5)
#pragma unroll
    for (int mask = 8; mask <= 32; mask <<= 1) {
        s_sum += __shfl_xor(s_sum, mask);
#pragma unroll
        for (int j = 0; j < 16; ++j) acc[j] += __shfl_xor(acc[j], mask);
    }
    float inv = (s_sum > 0.0f) ? 1.0f / s_sum : 0.0f;   // empty row -> zeros

    if (g8 == 0) {
        float* dst = out + (size_t)row * DIM + l8 * 16;
#pragma unroll
        for (int c = 0; c < 4; ++c) {
            float4 o = make_float4(acc[c*4+0] * inv, acc[c*4+1] * inv,
                                   acc[c*4+2] * inv, acc[c*4+3] * inv);
            *(float4*)(dst + c * 4) = o;
        }
    }
}

// ---------------------------------------------------------------------------
extern "C" void kernel_launch(void* const* d_in, const int* in_sizes, int n_in,
                              void* d_out, int out_size, void* d_ws, size_t ws_size,
                              hipStream_t stream)
{
    const float* query    = (const float*)d_in[0];
    const float* memory   = (const float*)d_in[1];
    const float* adj_vals = (const float*)d_in[2];
    const float* Wq       = (const float*)d_in[3];
    const float* bq       = (const float*)d_in[4];
    const float* Wk       = (const float*)d_in[5];
    const float* bk       = (const float*)d_in[6];
    const float* Wv       = (const float*)d_in[7];
    const float* bv       = (const float*)d_in[8];
    const int*   rows     = (const int*)d_in[9];
    const int*   cols     = (const int*)d_in[10];
    float* out = (float*)d_out;

    int n = in_sizes[0] / DIM;   // 50000
    int m = in_sizes[1] / DIM;   // 50000
    int e = in_sizes[9];         // 1600000

    // workspace layout (16B-aligned)
    char* ws = (char*)d_ws;
    size_t off = 0;
    _Float16* Wt = (_Float16*)(ws + off); off += (size_t)3 * DIM * DIM * 2;    // 98304
    _Float16* qf = (_Float16*)(ws + off); off += (size_t)n * DIM * 2;          // 12.8MB
    _Float16* kv = (_Float16*)(ws + off); off += (size_t)m * 2 * DIM * 2;      // 25.6MB

    prep_w_kernel<<<dim3(64, 3), 256, 0, stream>>>(Wq, Wk, Wv, Wt);

    proj_gemm_kernel<<<dim3((n + 127) / 128, 3), 256, 0, stream>>>(
        query, memory, Wt, bq, bk, bv, qf, kv, n, m);

    edge_attn_kernel<<<dim3((n + 3) / 4), 256, 0, stream>>>(
        (const __fp16*)qf, (const __fp16*)kv, adj_vals, cols, rows, out, n, e);
}

// Round 5
// 260.241 us; speedup vs baseline: 1.2187x; 1.2187x over previous
//
#include <hip/hip_runtime.h>
#include <hip/hip_bf16.h>
#include <math.h>

typedef _Float16 f16x4 __attribute__((ext_vector_type(4)));
typedef _Float16 f16x8 __attribute__((ext_vector_type(8)));
typedef float f32x4 __attribute__((ext_vector_type(4)));
typedef __fp16 hf2 __attribute__((ext_vector_type(2)));
typedef __fp16 hf8 __attribute__((ext_vector_type(8)));

struct hf2x4 { hf2 a, b, c, d; };   // 16B view of hf8 as 4 half2s

#define DIM 128
#define LDST 136   // padded LDS row stride in f16 elems (272B, 16B-aligned)

// ---------------------------------------------------------------------------
// Kernel 1: transpose + f16-convert the three 128x128 weight matrices.
// ---------------------------------------------------------------------------
__global__ __launch_bounds__(256) void prep_w_kernel(
    const float* __restrict__ Wq, const float* __restrict__ Wk,
    const float* __restrict__ Wv, _Float16* __restrict__ Wt)
{
    const float* W = (blockIdx.y == 0) ? Wq : (blockIdx.y == 1) ? Wk : Wv;
    _Float16* dst = Wt + (size_t)blockIdx.y * DIM * DIM;
    int idx = blockIdx.x * 256 + threadIdx.x;
    int k = idx >> 7;
    int n = idx & 127;
    dst[n * DIM + k] = (_Float16)W[idx];
}

// ---------------------------------------------------------------------------
// Kernel 2: CSR row_ptr from sorted rows[] via per-row lower_bound.
// (R4 post-mortem: fusing this as a per-wave serial binary search in the
//  edge kernel cost ~68 us of latency stall — keep it a separate dispatch.)
// ---------------------------------------------------------------------------
__global__ __launch_bounds__(256) void row_ptr_kernel(
    const int* __restrict__ rows, int* __restrict__ row_ptr, int n, int e)
{
    int r = blockIdx.x * 256 + threadIdx.x;
    if (r > n) return;
    if (r == n) { row_ptr[n] = e; return; }
    int lo = 0, hi = e;
    while (lo < hi) {
        int mid = (lo + hi) >> 1;
        if (rows[mid] < r) lo = mid + 1; else hi = mid;
    }
    row_ptr[r] = lo;
}

// ---------------------------------------------------------------------------
// Kernel 3: fused projection GEMM  Y = gelu(X @ W + b), output f16.
// (unchanged from R3 — coalesced LDS-staged A, MFMA, LDS-transposed epilogue)
// ---------------------------------------------------------------------------
__global__ __launch_bounds__(256, 2) void proj_gemm_kernel(
    const float* __restrict__ query, const float* __restrict__ memory,
    const _Float16* __restrict__ Wt,
    const float* __restrict__ bq, const float* __restrict__ bk,
    const float* __restrict__ bv,
    _Float16* __restrict__ qf, _Float16* __restrict__ kv, int n, int m)
{
    __shared__ _Float16 xs[128 * LDST];   // 34816 B

    int which = blockIdx.y;
    const float* X    = (which == 0) ? query : memory;
    const _Float16* Wm = Wt + (size_t)which * DIM * DIM;
    const float* bias = (which == 0) ? bq : (which == 1) ? bk : bv;
    int R             = (which == 0) ? n : m;
    _Float16* Ybase   = (which == 0) ? qf : (which == 2) ? kv + DIM : kv;
    size_t Ystride    = (which == 0) ? DIM : 2 * DIM;

    int tid = threadIdx.x;
    int rowblock = blockIdx.x * 128;
    if (rowblock >= R) return;

    for (int it = 0; it < 16; ++it) {
        int flat = it * 256 + tid;
        int r  = flat >> 5;
        int c4 = (flat & 31) * 4;
        int gr = rowblock + r;
        if (gr >= R) gr = R - 1;
        float4 x = *(const float4*)(X + (size_t)gr * DIM + c4);
        f16x4 w4;
        w4[0] = (_Float16)x.x; w4[1] = (_Float16)x.y;
        w4[2] = (_Float16)x.z; w4[3] = (_Float16)x.w;
        *(f16x4*)(&xs[r * LDST + c4]) = w4;
    }
    __syncthreads();

    int wave = tid >> 6;
    int lane = tid & 63;
    int quad = lane >> 4;
    int l16  = lane & 15;
    int wrow = wave * 32;

    f16x8 afrag[2][4];
    for (int rt = 0; rt < 2; ++rt)
        for (int ks = 0; ks < 4; ++ks)
            afrag[rt][ks] = *(const f16x8*)(&xs[(wrow + rt * 16 + l16) * LDST + quad * 8 + ks * 32]);

    f32x4 acc[8][2];
    for (int ct = 0; ct < 8; ++ct) { acc[ct][0] = {0,0,0,0}; acc[ct][1] = {0,0,0,0}; }
    for (int ct = 0; ct < 8; ++ct) {
        const _Float16* wp = Wm + (size_t)(ct * 16 + l16) * DIM + quad * 8;
        for (int ks = 0; ks < 4; ++ks) {
            f16x8 b = *(const f16x8*)(wp + ks * 32);
            acc[ct][0] = __builtin_amdgcn_mfma_f32_16x16x32_f16(afrag[0][ks], b, acc[ct][0], 0, 0, 0);
            acc[ct][1] = __builtin_amdgcn_mfma_f32_16x16x32_f16(afrag[1][ks], b, acc[ct][1], 0, 0, 0);
        }
    }

    __syncthreads();
    for (int ct = 0; ct < 8; ++ct) {
        float bval = bias[ct * 16 + l16];
        for (int rt = 0; rt < 2; ++rt) {
            for (int reg = 0; reg < 4; ++reg) {
                float x = acc[ct][rt][reg] + bval;
                float t  = 0.7978845608028654f * (x + 0.044715f * x * x * x);
                float th = 1.0f - 2.0f / (__expf(2.0f * t) + 1.0f);
                float g  = 0.5f * x * (1.0f + th);
                xs[(wrow + rt * 16 + quad * 4 + reg) * LDST + ct * 16 + l16] = (_Float16)g;
            }
        }
    }
    __syncthreads();

    for (int it = 0; it < 8; ++it) {
        int flat = it * 256 + tid;
        int r  = flat >> 4;
        int c8 = (flat & 15) * 8;
        int gr = rowblock + r;
        if (gr < R) {
            f16x8 vv = *(const f16x8*)(&xs[r * LDST + c8]);
            *(f16x8*)(Ybase + (size_t)gr * Ystride + c8) = vv;
        }
    }
}

// ---------------------------------------------------------------------------
// Kernel 4: per-row edge attention. One wave per row (R3 skeleton: 16
// lanes/edge via quarter=lane>>4, l16 picks 8 dims, 8 edges in flight).
// Changes vs R3: plain exp (no online softmax — scores are O(1), overflow
// impossible, identical result in fp32) and v_dot2_f32_f16 for the q.k dot.
// kv interleaved: 512B record per col.
// ---------------------------------------------------------------------------
#if defined(__has_builtin)
#if __has_builtin(__builtin_amdgcn_fdot2)
#define HAVE_FDOT2 1
#endif
#endif

__device__ __forceinline__ void dot8(float& d, hf8 k8, hf8 q8) {
#ifdef HAVE_FDOT2
    hf2x4 K = __builtin_bit_cast(hf2x4, k8);
    hf2x4 Q = __builtin_bit_cast(hf2x4, q8);
    d = __builtin_amdgcn_fdot2(K.a, Q.a, d, false);
    d = __builtin_amdgcn_fdot2(K.b, Q.b, d, false);
    d = __builtin_amdgcn_fdot2(K.c, Q.c, d, false);
    d = __builtin_amdgcn_fdot2(K.d, Q.d, d, false);
#else
#pragma unroll
    for (int j = 0; j < 8; ++j) d += (float)k8[j] * (float)q8[j];
#endif
}

__global__ __launch_bounds__(256) void edge_attn_kernel(
    const __fp16* __restrict__ qf, const __fp16* __restrict__ kv,
    const float* __restrict__ adj_vals, const int* __restrict__ cols,
    const int* __restrict__ row_ptr, float* __restrict__ out, int n)
{
    int row = blockIdx.x * 4 + (threadIdx.x >> 6);
    if (row >= n) return;
    int lane    = threadIdx.x & 63;
    int quarter = lane >> 4;
    int l16     = lane & 15;

    int start = row_ptr[row];
    int end   = row_ptr[row + 1];

    hf8 q8 = *(const hf8*)(qf + (size_t)row * DIM + l16 * 8);

    float s_sum = 0.0f;
    float acc[8];
#pragma unroll
    for (int j = 0; j < 8; ++j) acc[j] = 0.0f;

    const float scale = 0.08838834764831845f;   // 1/sqrt(128)

    for (int g = start; g < end; g += 8) {
        int eA = g + quarter;
        int eB = g + 4 + quarter;
        bool vA = eA < end;
        bool vB = eB < end;
        int last = end - 1;
        int iA = vA ? eA : last;
        int iB = vB ? eB : last;
        int   cA = cols[iA];
        int   cB = cols[iB];
        float aA = adj_vals[iA] * scale;
        float aB = adj_vals[iB] * scale;

        const __fp16* pA = kv + (size_t)cA * 256 + l16 * 8;
        const __fp16* pB = kv + (size_t)cB * 256 + l16 * 8;
        hf8 kA = *(const hf8*)pA;
        hf8 vA8 = *(const hf8*)(pA + 128);
        hf8 kB = *(const hf8*)pB;
        hf8 vB8 = *(const hf8*)(pB + 128);

        float dA = 0.0f, dB = 0.0f;
        dot8(dA, kA, q8);
        dot8(dB, kB, q8);
        dA += __shfl_xor(dA, 1); dB += __shfl_xor(dB, 1);
        dA += __shfl_xor(dA, 2); dB += __shfl_xor(dB, 2);
        dA += __shfl_xor(dA, 4); dB += __shfl_xor(dB, 4);
        dA += __shfl_xor(dA, 8); dB += __shfl_xor(dB, 8);

        float pA_ = vA ? __expf(dA * aA) : 0.0f;
        float pB_ = vB ? __expf(dB * aB) : 0.0f;
        s_sum += pA_ + pB_;
#pragma unroll
        for (int j = 0; j < 8; ++j)
            acc[j] += pA_ * (float)vA8[j] + pB_ * (float)vB8[j];
    }

    // merge the 4 quarter groups
    s_sum += __shfl_xor(s_sum, 16);
    s_sum += __shfl_xor(s_sum, 32);
#pragma unroll
    for (int j = 0; j < 8; ++j) {
        acc[j] += __shfl_xor(acc[j], 16);
        acc[j] += __shfl_xor(acc[j], 32);
    }
    float inv = (s_sum > 0.0f) ? 1.0f / s_sum : 0.0f;   // empty row -> zeros

    if (quarter == 0) {
        float4* dst = (float4*)(out + (size_t)row * DIM + l16 * 8);
        dst[0] = make_float4(acc[0] * inv, acc[1] * inv, acc[2] * inv, acc[3] * inv);
        dst[1] = make_float4(acc[4] * inv, acc[5] * inv, acc[6] * inv, acc[7] * inv);
    }
}

// ---------------------------------------------------------------------------
extern "C" void kernel_launch(void* const* d_in, const int* in_sizes, int n_in,
                              void* d_out, int out_size, void* d_ws, size_t ws_size,
                              hipStream_t stream)
{
    const float* query    = (const float*)d_in[0];
    const float* memory   = (const float*)d_in[1];
    const float* adj_vals = (const float*)d_in[2];
    const float* Wq       = (const float*)d_in[3];
    const float* bq       = (const float*)d_in[4];
    const float* Wk       = (const float*)d_in[5];
    const float* bk       = (const float*)d_in[6];
    const float* Wv       = (const float*)d_in[7];
    const float* bv       = (const float*)d_in[8];
    const int*   rows     = (const int*)d_in[9];
    const int*   cols     = (const int*)d_in[10];
    float* out = (float*)d_out;

    int n = in_sizes[0] / DIM;   // 50000
    int m = in_sizes[1] / DIM;   // 50000
    int e = in_sizes[9];         // 1600000

    // workspace layout (16B-aligned)
    char* ws = (char*)d_ws;
    size_t off = 0;
    _Float16* Wt = (_Float16*)(ws + off); off += (size_t)3 * DIM * DIM * 2;    // 98304
    _Float16* qf = (_Float16*)(ws + off); off += (size_t)n * DIM * 2;          // 12.8MB
    _Float16* kv = (_Float16*)(ws + off); off += (size_t)m * 2 * DIM * 2;      // 25.6MB
    int* row_ptr = (int*)(ws + off);      off += (size_t)(n + 1) * 4;

    prep_w_kernel<<<dim3(64, 3), 256, 0, stream>>>(Wq, Wk, Wv, Wt);

    row_ptr_kernel<<<dim3((n + 1 + 255) / 256), 256, 0, stream>>>(rows, row_ptr, n, e);

    proj_gemm_kernel<<<dim3((n + 127) / 128, 3), 256, 0, stream>>>(
        query, memory, Wt, bq, bk, bv, qf, kv, n, m);

    edge_attn_kernel<<<dim3((n + 3) / 4), 256, 0, stream>>>(
        (const __fp16*)qf, (const __fp16*)kv, adj_vals, cols, row_ptr, out, n);
}

// Round 6
// 235.277 us; speedup vs baseline: 1.3480x; 1.1061x over previous
//
#include <hip/hip_runtime.h>
#include <hip/hip_bf16.h>
#include <hip/hip_fp8.h>
#include <math.h>

typedef _Float16 f16x4 __attribute__((ext_vector_type(4)));
typedef _Float16 f16x8 __attribute__((ext_vector_type(8)));
typedef float f32x4 __attribute__((ext_vector_type(4)));
typedef __fp16 hf8 __attribute__((ext_vector_type(8)));

#define DIM 128
#define LDST 136   // padded LDS row stride in f16 elems (272B, 16B-aligned)

#if defined(__has_builtin)
#if __has_builtin(__builtin_amdgcn_cvt_pk_fp8_f32) && __has_builtin(__builtin_amdgcn_cvt_pk_f32_fp8)
#define HAVE_FP8CVT 1
#endif
#endif

// pack 4 floats -> 4 fp8 e4m3 bytes in a uint
__device__ __forceinline__ unsigned int pack_fp8x4(float f0, float f1, float f2, float f3) {
#ifdef HAVE_FP8CVT
    int w = __builtin_amdgcn_cvt_pk_fp8_f32(f0, f1, 0, false);
    w = __builtin_amdgcn_cvt_pk_fp8_f32(f2, f3, w, true);
    return (unsigned int)w;
#else
    __hip_fp8_e4m3 a(f0), b(f1), c(f2), d(f3);
    return (unsigned int)a.__x | ((unsigned int)b.__x << 8) |
           ((unsigned int)c.__x << 16) | ((unsigned int)d.__x << 24);
#endif
}

// unpack 4 fp8 e4m3 bytes -> two float2-likes accumulated into dot with q
__device__ __forceinline__ void dot_fp8x4(float& d, unsigned int w, const float* qv) {
#ifdef HAVE_FP8CVT
    auto lo = __builtin_amdgcn_cvt_pk_f32_fp8((int)w, false);
    auto hi = __builtin_amdgcn_cvt_pk_f32_fp8((int)w, true);
    d += lo[0] * qv[0] + lo[1] * qv[1] + hi[0] * qv[2] + hi[1] * qv[3];
#else
    for (int j = 0; j < 4; ++j) {
        __hip_fp8_e4m3 t; t.__x = (unsigned char)((w >> (8 * j)) & 0xff);
        d += (float)t * qv[j];
    }
#endif
}

// ---------------------------------------------------------------------------
// Kernel 1: transpose + f16-convert the three 128x128 weight matrices.
// ---------------------------------------------------------------------------
__global__ __launch_bounds__(256) void prep_w_kernel(
    const float* __restrict__ Wq, const float* __restrict__ Wk,
    const float* __restrict__ Wv, _Float16* __restrict__ Wt)
{
    const float* W = (blockIdx.y == 0) ? Wq : (blockIdx.y == 1) ? Wk : Wv;
    _Float16* dst = Wt + (size_t)blockIdx.y * DIM * DIM;
    int idx = blockIdx.x * 256 + threadIdx.x;
    int k = idx >> 7;
    int n = idx & 127;
    dst[n * DIM + k] = (_Float16)W[idx];
}

// ---------------------------------------------------------------------------
// Kernel 2: CSR row_ptr from sorted rows[] via per-row lower_bound.
// ---------------------------------------------------------------------------
__global__ __launch_bounds__(256) void row_ptr_kernel(
    const int* __restrict__ rows, int* __restrict__ row_ptr, int n, int e)
{
    int r = blockIdx.x * 256 + threadIdx.x;
    if (r > n) return;
    if (r == n) { row_ptr[n] = e; return; }
    int lo = 0, hi = e;
    while (lo < hi) {
        int mid = (lo + hi) >> 1;
        if (rows[mid] < r) lo = mid + 1; else hi = mid;
    }
    row_ptr[r] = lo;
}

// ---------------------------------------------------------------------------
// Kernel 3: fused projection GEMM  Y = gelu(X @ W + b).
// which==0 -> qf (f16), which==1 -> k8 (fp8 e4m3), which==2 -> v16 (f16).
// Coalesced LDS-staged A, MFMA, LDS-transposed epilogue (R3 structure).
// ---------------------------------------------------------------------------
__global__ __launch_bounds__(256, 2) void proj_gemm_kernel(
    const float* __restrict__ query, const float* __restrict__ memory,
    const _Float16* __restrict__ Wt,
    const float* __restrict__ bq, const float* __restrict__ bk,
    const float* __restrict__ bv,
    _Float16* __restrict__ qf, unsigned char* __restrict__ k8,
    _Float16* __restrict__ v16, int n, int m)
{
    __shared__ _Float16 xs[128 * LDST];   // 34816 B

    int which = blockIdx.y;
    const float* X    = (which == 0) ? query : memory;
    const _Float16* Wm = Wt + (size_t)which * DIM * DIM;
    const float* bias = (which == 0) ? bq : (which == 1) ? bk : bv;
    int R             = (which == 0) ? n : m;

    int tid = threadIdx.x;
    int rowblock = blockIdx.x * 128;
    if (rowblock >= R) return;

    for (int it = 0; it < 16; ++it) {
        int flat = it * 256 + tid;
        int r  = flat >> 5;
        int c4 = (flat & 31) * 4;
        int gr = rowblock + r;
        if (gr >= R) gr = R - 1;
        float4 x = *(const float4*)(X + (size_t)gr * DIM + c4);
        f16x4 w4;
        w4[0] = (_Float16)x.x; w4[1] = (_Float16)x.y;
        w4[2] = (_Float16)x.z; w4[3] = (_Float16)x.w;
        *(f16x4*)(&xs[r * LDST + c4]) = w4;
    }
    __syncthreads();

    int wave = tid >> 6;
    int lane = tid & 63;
    int quad = lane >> 4;
    int l16  = lane & 15;
    int wrow = wave * 32;

    f16x8 afrag[2][4];
    for (int rt = 0; rt < 2; ++rt)
        for (int ks = 0; ks < 4; ++ks)
            afrag[rt][ks] = *(const f16x8*)(&xs[(wrow + rt * 16 + l16) * LDST + quad * 8 + ks * 32]);

    f32x4 acc[8][2];
    for (int ct = 0; ct < 8; ++ct) { acc[ct][0] = {0,0,0,0}; acc[ct][1] = {0,0,0,0}; }
    for (int ct = 0; ct < 8; ++ct) {
        const _Float16* wp = Wm + (size_t)(ct * 16 + l16) * DIM + quad * 8;
        for (int ks = 0; ks < 4; ++ks) {
            f16x8 b = *(const f16x8*)(wp + ks * 32);
            acc[ct][0] = __builtin_amdgcn_mfma_f32_16x16x32_f16(afrag[0][ks], b, acc[ct][0], 0, 0, 0);
            acc[ct][1] = __builtin_amdgcn_mfma_f32_16x16x32_f16(afrag[1][ks], b, acc[ct][1], 0, 0, 0);
        }
    }

    __syncthreads();
    for (int ct = 0; ct < 8; ++ct) {
        float bval = bias[ct * 16 + l16];
        for (int rt = 0; rt < 2; ++rt) {
            for (int reg = 0; reg < 4; ++reg) {
                float x = acc[ct][rt][reg] + bval;
                float t  = 0.7978845608028654f * (x + 0.044715f * x * x * x);
                float th = 1.0f - 2.0f / (__expf(2.0f * t) + 1.0f);
                float g  = 0.5f * x * (1.0f + th);
                xs[(wrow + rt * 16 + quad * 4 + reg) * LDST + ct * 16 + l16] = (_Float16)g;
            }
        }
    }
    __syncthreads();

    if (which == 1) {
        // fp8 e4m3 output: 8 f16 -> 8 bytes per chunk, coalesced 8B stores
        for (int it = 0; it < 8; ++it) {
            int flat = it * 256 + tid;
            int r  = flat >> 4;
            int c8 = (flat & 15) * 8;
            int gr = rowblock + r;
            if (gr < R) {
                f16x8 h = *(const f16x8*)(&xs[r * LDST + c8]);
                unsigned int w0 = pack_fp8x4((float)h[0], (float)h[1], (float)h[2], (float)h[3]);
                unsigned int w1 = pack_fp8x4((float)h[4], (float)h[5], (float)h[6], (float)h[7]);
                *(uint2*)(k8 + (size_t)gr * DIM + c8) = make_uint2(w0, w1);
            }
        }
    } else {
        _Float16* Ybase = (which == 0) ? qf : v16;
        for (int it = 0; it < 8; ++it) {
            int flat = it * 256 + tid;
            int r  = flat >> 4;
            int c8 = (flat & 15) * 8;
            int gr = rowblock + r;
            if (gr < R) {
                f16x8 vv = *(const f16x8*)(&xs[r * LDST + c8]);
                *(f16x8*)(Ybase + (size_t)gr * DIM + c8) = vv;
            }
        }
    }
}

// ---------------------------------------------------------------------------
// Kernel 4: per-row edge attention. One wave per row (R5 skeleton: 16
// lanes/edge, quarter=lane>>4, l16 picks 8 dims, 8 edges in flight, plain
// exp). Change vs R5: k gathered as fp8 e4m3 (8B/lane) — halves the k
// gather traffic and shrinks the k working set to 6.4MB (L2-friendly).
// ---------------------------------------------------------------------------
__global__ __launch_bounds__(256) void edge_attn_kernel(
    const __fp16* __restrict__ qf, const unsigned char* __restrict__ k8,
    const __fp16* __restrict__ v16, const float* __restrict__ adj_vals,
    const int* __restrict__ cols, const int* __restrict__ row_ptr,
    float* __restrict__ out, int n)
{
    int row = blockIdx.x * 4 + (threadIdx.x >> 6);
    if (row >= n) return;
    int lane    = threadIdx.x & 63;
    int quarter = lane >> 4;
    int l16     = lane & 15;

    int start = row_ptr[row];
    int end   = row_ptr[row + 1];

    float qv[8];
    {
        hf8 q8 = *(const hf8*)(qf + (size_t)row * DIM + l16 * 8);
#pragma unroll
        for (int j = 0; j < 8; ++j) qv[j] = (float)q8[j];
    }

    float s_sum = 0.0f;
    float acc[8];
#pragma unroll
    for (int j = 0; j < 8; ++j) acc[j] = 0.0f;

    const float scale = 0.08838834764831845f;   // 1/sqrt(128)

    for (int g = start; g < end; g += 8) {
        int eA = g + quarter;
        int eB = g + 4 + quarter;
        bool vA = eA < end;
        bool vB = eB < end;
        int last = end - 1;
        int iA = vA ? eA : last;
        int iB = vB ? eB : last;
        int   cA = cols[iA];
        int   cB = cols[iB];
        float aA = adj_vals[iA] * scale;
        float aB = adj_vals[iB] * scale;

        uint2 rA = *(const uint2*)(k8 + (size_t)cA * DIM + l16 * 8);
        uint2 rB = *(const uint2*)(k8 + (size_t)cB * DIM + l16 * 8);
        hf8 vA8 = *(const hf8*)(v16 + (size_t)cA * DIM + l16 * 8);
        hf8 vB8 = *(const hf8*)(v16 + (size_t)cB * DIM + l16 * 8);

        float dA = 0.0f, dB = 0.0f;
        dot_fp8x4(dA, rA.x, qv);
        dot_fp8x4(dA, rA.y, qv + 4);
        dot_fp8x4(dB, rB.x, qv);
        dot_fp8x4(dB, rB.y, qv + 4);
        dA += __shfl_xor(dA, 1); dB += __shfl_xor(dB, 1);
        dA += __shfl_xor(dA, 2); dB += __shfl_xor(dB, 2);
        dA += __shfl_xor(dA, 4); dB += __shfl_xor(dB, 4);
        dA += __shfl_xor(dA, 8); dB += __shfl_xor(dB, 8);

        float pA_ = vA ? __expf(dA * aA) : 0.0f;
        float pB_ = vB ? __expf(dB * aB) : 0.0f;
        s_sum += pA_ + pB_;
#pragma unroll
        for (int j = 0; j < 8; ++j)
            acc[j] += pA_ * (float)vA8[j] + pB_ * (float)vB8[j];
    }

    // merge the 4 quarter groups
    s_sum += __shfl_xor(s_sum, 16);
    s_sum += __shfl_xor(s_sum, 32);
#pragma unroll
    for (int j = 0; j < 8; ++j) {
        acc[j] += __shfl_xor(acc[j], 16);
        acc[j] += __shfl_xor(acc[j], 32);
    }
    float inv = (s_sum > 0.0f) ? 1.0f / s_sum : 0.0f;   // empty row -> zeros

    if (quarter == 0) {
        float4* dst = (float4*)(out + (size_t)row * DIM + l16 * 8);
        dst[0] = make_float4(acc[0] * inv, acc[1] * inv, acc[2] * inv, acc[3] * inv);
        dst[1] = make_float4(acc[4] * inv, acc[5] * inv, acc[6] * inv, acc[7] * inv);
    }
}

// ---------------------------------------------------------------------------
extern "C" void kernel_launch(void* const* d_in, const int* in_sizes, int n_in,
                              void* d_out, int out_size, void* d_ws, size_t ws_size,
                              hipStream_t stream)
{
    const float* query    = (const float*)d_in[0];
    const float* memory   = (const float*)d_in[1];
    const float* adj_vals = (const float*)d_in[2];
    const float* Wq       = (const float*)d_in[3];
    const float* bq       = (const float*)d_in[4];
    const float* Wk       = (const float*)d_in[5];
    const float* bk       = (const float*)d_in[6];
    const float* Wv       = (const float*)d_in[7];
    const float* bv       = (const float*)d_in[8];
    const int*   rows     = (const int*)d_in[9];
    const int*   cols     = (const int*)d_in[10];
    float* out = (float*)d_out;

    int n = in_sizes[0] / DIM;   // 50000
    int m = in_sizes[1] / DIM;   // 50000
    int e = in_sizes[9];         // 1600000

    // workspace layout (16B-aligned)
    char* ws = (char*)d_ws;
    size_t off = 0;
    _Float16* Wt = (_Float16*)(ws + off); off += (size_t)3 * DIM * DIM * 2;    // 98304
    _Float16* qf = (_Float16*)(ws + off); off += (size_t)n * DIM * 2;          // 12.8MB
    _Float16* v16 = (_Float16*)(ws + off); off += (size_t)m * DIM * 2;         // 12.8MB
    unsigned char* k8 = (unsigned char*)(ws + off); off += (size_t)m * DIM;    // 6.4MB
    int* row_ptr = (int*)(ws + off);      off += (size_t)(n + 1) * 4;

    prep_w_kernel<<<dim3(64, 3), 256, 0, stream>>>(Wq, Wk, Wv, Wt);

    row_ptr_kernel<<<dim3((n + 1 + 255) / 256), 256, 0, stream>>>(rows, row_ptr, n, e);

    proj_gemm_kernel<<<dim3((n + 127) / 128, 3), 256, 0, stream>>>(
        query, memory, Wt, bq, bk, bv, qf, k8, v16, n, m);

    edge_attn_kernel<<<dim3((n + 3) / 4), 256, 0, stream>>>(
        (const __fp16*)qf, k8, (const __fp16*)v16, adj_vals, cols, row_ptr, out, n);
}